// Round 6
// baseline (768.820 us; speedup 1.0000x reference)
//
#include <hip/hip_runtime.h>

typedef _Float16 f16;
typedef _Float16 f16x8 __attribute__((ext_vector_type(8)));
typedef _Float16 f16x4 __attribute__((ext_vector_type(4)));
typedef float f32x4 __attribute__((ext_vector_type(4)));

#define B_ 512
#define L_ 512
#define Cc_ 64
#define Ct_ 16
#define Co_ 8
#define H_ 128
#define IN_ 88
#define KP 96       // padded K for MFMA
#define G3 384      // 3*H
#define R_ 16       // batch rows per scan block / gemm tile

#define L2E  1.44269504088896f   // log2(e)
#define L2E2 2.88539008177793f   // 2*log2(e)

// Fragment-ordered gi: giF[g0][l][n0=0..23][q=0..3][c=0..15][e=0..3] (f16)
//   unit u = n0*16 + 4q + e, gate g = n0>>3, batch b = g0*16 + c.

// ---------------- K0: W_ih -> A-fragment order (scaled); bias -> f32 (scaled, b_hh folded) ----
__global__ void k_prep(const float* __restrict__ Wih,
                       const float* __restrict__ bih, const float* __restrict__ bhh,
                       f16* __restrict__ WAf, float* __restrict__ biasF) {
    int idx = blockIdx.x * 256 + threadIdx.x;
    if (idx < G3 * KP) {                       // 36864 WAf elements
        int n0 = idx / 1536;
        int rem = idx - n0 * 1536;
        int ks = rem >> 9;
        int rem2 = rem & 511;
        int lane = rem2 >> 3, j = rem2 & 7;
        int unit = n0 * 16 + (lane & 15);
        int k = ((lane >> 4) << 3) + 32 * ks + j;
        float s = (n0 < 16) ? L2E : L2E2;
        WAf[idx] = (k < IN_) ? (f16)(Wih[unit * IN_ + k] * s) : (f16)0.f;
    } else if (idx < G3 * KP + G3) {           // 384 biases
        int u = idx - G3 * KP;
        biasF[u] = (u < 256) ? (bih[u] + bhh[u]) * L2E : bih[u] * L2E2;
    }
}

// ---------------- K1: time-norm + concat -> f16, TRANSPOSED [g0][l][c][96] ----------------
__global__ __launch_bounds__(256) void k_norm(
        const float* __restrict__ cov, const float* __restrict__ tr, const float* __restrict__ oc,
        const float* __restrict__ g_t, const float* __restrict__ bt,
        const float* __restrict__ g_o, const float* __restrict__ bo,
        const float* __restrict__ g_c, const float* __restrict__ bc,
        f16* __restrict__ inpT) {
    int b = blockIdx.x, t = threadIdx.x;
    __shared__ float ps[256], ps2[256];
    __shared__ float sc[88], sh[88];   // concat order: t[0:16), o[16:24), c[24:88)

    { // covariates, C=64, 4 l-groups
        int c = t & 63, lg = t >> 6;
        const float* p = cov + (size_t)b * L_ * Cc_ + c;
        float s = 0.f, s2 = 0.f;
        for (int i = lg; i < L_; i += 4) { float v = p[(size_t)i * Cc_]; s += v; s2 += v * v; }
        ps[t] = s; ps2[t] = s2; __syncthreads();
        if (t < 64) {
            float S = 0.f, S2 = 0.f;
            for (int g = 0; g < 4; g++) { S += ps[t + 64 * g]; S2 += ps2[t + 64 * g]; }
            float m = S * (1.f / L_), v = S2 * (1.f / L_) - m * m;
            float inv = rsqrtf(v + 1e-5f);
            float gg = g_c[t] * inv;
            sc[24 + t] = gg; sh[24 + t] = bc[t] - m * gg;
        }
        __syncthreads();
    }
    { // treatments, C=16, 16 l-groups
        int c = t & 15, lg = t >> 4;
        const float* p = tr + (size_t)b * L_ * Ct_ + c;
        float s = 0.f, s2 = 0.f;
        for (int i = lg; i < L_; i += 16) { float v = p[(size_t)i * Ct_]; s += v; s2 += v * v; }
        ps[t] = s; ps2[t] = s2; __syncthreads();
        if (t < 16) {
            float S = 0.f, S2 = 0.f;
            for (int g = 0; g < 16; g++) { S += ps[t + 16 * g]; S2 += ps2[t + 16 * g]; }
            float m = S * (1.f / L_), v = S2 * (1.f / L_) - m * m;
            float inv = rsqrtf(v + 1e-5f);
            float gg = g_t[t] * inv;
            sc[t] = gg; sh[t] = bt[t] - m * gg;
        }
        __syncthreads();
    }
    { // outcomes, C=8, 32 l-groups
        int c = t & 7, lg = t >> 3;
        const float* p = oc + (size_t)b * L_ * Co_ + c;
        float s = 0.f, s2 = 0.f;
        for (int i = lg; i < L_; i += 32) { float v = p[(size_t)i * Co_]; s += v; s2 += v * v; }
        ps[t] = s; ps2[t] = s2; __syncthreads();
        if (t < 8) {
            float S = 0.f, S2 = 0.f;
            for (int g = 0; g < 32; g++) { S += ps[t + 8 * g]; S2 += ps2[t + 8 * g]; }
            float m = S * (1.f / L_), v = S2 * (1.f / L_) - m * m;
            float inv = rsqrtf(v + 1e-5f);
            float gg = g_o[t] * inv;
            sc[16 + t] = gg; sh[16 + t] = bo[t] - m * gg;
        }
        __syncthreads();
    }
    // phase B: normalize + concat + pad -> inpT[((b>>4)*512 + l)*16 + (b&15)][96]
    f16* outp = inpT + ((size_t)(b >> 4) * L_ * 16 + (b & 15)) * KP;
    for (int idx = t; idx < L_ * KP; idx += 256) {
        int l = idx / KP, cc = idx % KP;
        float y = 0.f;
        if (cc < 88) {
            float x;
            if (cc < 16)      x = tr[((size_t)b * L_ + l) * Ct_ + cc];
            else if (cc < 24) x = oc[((size_t)b * L_ + l) * Co_ + (cc - 16)];
            else              x = cov[((size_t)b * L_ + l) * Cc_ + (cc - 24)];
            y = x * sc[cc] + sh[cc];
        }
        outp[(size_t)l * 16 * KP + cc] = (f16)y;
    }
}

// ---------------- K2: gi GEMM, fragment-ordered output. ---------------------------------
__global__ __launch_bounds__(256) void k_gemm(
        const f16* __restrict__ inpT, const f16* __restrict__ WAf,
        const float* __restrict__ biasF, f16* __restrict__ giF) {
    const int g0 = blockIdx.x >> 7;
    const int l  = ((blockIdx.x & 127) << 2) + (threadIdx.x >> 6);
    const int lane = threadIdx.x & 63;
    const int c = lane & 15, q = lane >> 4;

    const f16* bp = inpT + (((size_t)g0 * L_ + l) * 16 + c) * KP + q * 8;
    f16x8 x0 = *(const f16x8*)(bp);
    f16x8 x1 = *(const f16x8*)(bp + 32);
    f16x8 x2 = *(const f16x8*)(bp + 64);

    const f16x8* wa = (const f16x8*)WAf;
    f16* gout = giF + ((size_t)g0 * L_ + l) * 24 * 256 + q * 64 + c * 4;

    #pragma unroll 4
    for (int n0 = 0; n0 < 24; n0++) {
        f16x8 a0 = wa[(n0 * 3 + 0) * 64 + lane];
        f16x8 a1 = wa[(n0 * 3 + 1) * 64 + lane];
        f16x8 a2 = wa[(n0 * 3 + 2) * 64 + lane];
        f32x4 acc = *(const f32x4*)(biasF + n0 * 16 + q * 4);
        acc = __builtin_amdgcn_mfma_f32_16x16x32_f16(a0, x0, acc, 0, 0, 0);
        acc = __builtin_amdgcn_mfma_f32_16x16x32_f16(a1, x1, acc, 0, 0, 0);
        acc = __builtin_amdgcn_mfma_f32_16x16x32_f16(a2, x2, acc, 0, 0, 0);
        f16x4 st = {(f16)acc[0], (f16)acc[1], (f16)acc[2], (f16)acc[3]};
        *(f16x4*)(gout + n0 * 256) = st;
    }
}

// ---------------- K3: GRU scan via MFMA. 16 rows/block, 4 waves, 32 units/wave. ---------
// DS h-broadcast halves vs 8-wave (16 KB/step); each lane computes 8 gate-elements
// (2 MFMA tiles per gate). Stage-out remapped to 256 threads (f16x8 LDS read + 2 f32x4).
__global__ __launch_bounds__(256, 1) void k_scan_mfma(
        const f16* __restrict__ giF, const float* __restrict__ Whh, const float* __restrict__ bhh,
        float* __restrict__ outA, float* __restrict__ outB, int rowBase) {
    const int t = threadIdx.x;
    const int w = t >> 6;          // wave 0..3: owns hidden units [32w, 32w+32)
    const int lane = t & 63;
    const int c = lane & 15;       // batch row within tile
    const int q = lane >> 4;       // 0..3
    const int q8 = q * 8;
    const int uD0 = 32 * w + 4 * q;             // tile-0 unit base in D
    const int uD1 = uD0 + 16;                   // tile-1 unit base

    __shared__ f16 hb0[R_ * H_];                // 4KB each, swizzled [b][k^((b&7)<<3)]
    __shared__ f16 hb1[R_ * H_];

    // persistent W_hh A-fragments: WA[gate][tile][ks]; unit = 32w+16tt+c, k = q8+32ks+j
    f16x8 WA[3][2][4];
    #pragma unroll
    for (int g = 0; g < 3; g++) {
        float s = (g < 2) ? L2E : L2E2;
        #pragma unroll
        for (int tt = 0; tt < 2; tt++)
            #pragma unroll
            for (int ks = 0; ks < 4; ks++) {
                const float* wp = Whh + (size_t)(g * H_ + 32 * w + 16 * tt + c) * H_ + q8 + 32 * ks;
                f16x8 v;
                #pragma unroll
                for (int j = 0; j < 8; j++) v[j] = (f16)(wp[j] * s);
                WA[g][tt][ks] = v;
            }
    }
    // n-gate b_hh, pre-scaled — aN accumulator init (per tile)
    const f32x4 bN0 = { L2E2 * bhh[2 * H_ + uD0 + 0], L2E2 * bhh[2 * H_ + uD0 + 1],
                        L2E2 * bhh[2 * H_ + uD0 + 2], L2E2 * bhh[2 * H_ + uD0 + 3] };
    const f32x4 bN1 = { L2E2 * bhh[2 * H_ + uD1 + 0], L2E2 * bhh[2 * H_ + uD1 + 1],
                        L2E2 * bhh[2 * H_ + uD1 + 2], L2E2 * bhh[2 * H_ + uD1 + 3] };

    for (int i = t; i < R_ * H_; i += 256) hb0[i] = (f16)0.f;
    float hp00 = 0.f, hp01 = 0.f, hp02 = 0.f, hp03 = 0.f;
    float hp10 = 0.f, hp11 = 0.f, hp12 = 0.f, hp13 = 0.f;

    // ---- coalesced output staging: thread -> (row, 8 contiguous units) ----
    const int srow = t >> 4;               // 0..15 (block-local row)
    const int se8  = (t & 15) * 8;         // unit base 0..120
    const int sswz = (srow & 7) << 3;
    const int grow = rowBase + blockIdx.x * R_ + srow;
    float* op; int ost;
    if (se8 == 0) { op = outA + (size_t)grow * L_ * Co_;                   ost = Co_; }
    else          { op = outB + (size_t)grow * L_ * (H_ - Co_) + (se8 - Co_); ost = H_ - Co_; }

    const int swzm = (c & 7) << 3;              // XOR swizzle mask (f16 index bits 3..5)
    // fragment-ordered gi pointer: wave-contiguous 512B loads per (gate,tile)
    const f16* gbase = giF + (size_t)blockIdx.x * L_ * 24 * 256 + (2 * w) * 256 + q * 64 + c * 4;

    // preload gi[0] into E buffers (gate stride 2048, tile stride 256)
    f16x4 gR0e = *(const f16x4*)(gbase + 0);
    f16x4 gR1e = *(const f16x4*)(gbase + 256);
    f16x4 gZ0e = *(const f16x4*)(gbase + 2048);
    f16x4 gZ1e = *(const f16x4*)(gbase + 2304);
    f16x4 gN0e = *(const f16x4*)(gbase + 4096);
    f16x4 gN1e = *(const f16x4*)(gbase + 4352);
    f16x4 gR0o, gR1o, gZ0o, gZ1o, gN0o, gN1o;

    __syncthreads();

#define GRU_STEP(HCUR, HNEXT, GR0, GR1, GZ0, GZ1, GN0, GN1, DOSTAGE)                \
    {                                                                               \
        if (DOSTAGE) {  /* store h_out(prev step), coalesced, f16-rounded */        \
            f16x8 sv = *(const f16x8*)(HCUR + srow * H_ + (se8 ^ sswz));            \
            f32x4 o0 = {(float)sv[0], (float)sv[1], (float)sv[2], (float)sv[3]};    \
            f32x4 o1 = {(float)sv[4], (float)sv[5], (float)sv[6], (float)sv[7]};    \
            *(f32x4*)op = o0;                                                       \
            *(f32x4*)(op + 4) = o1;                                                 \
            op += ost;                                                              \
        }                                                                           \
        f16x8 hB0 = *(const f16x8*)(HCUR + c * H_ + ((q8 +  0) ^ swzm));            \
        f16x8 hB1 = *(const f16x8*)(HCUR + c * H_ + ((q8 + 32) ^ swzm));            \
        f16x8 hB2 = *(const f16x8*)(HCUR + c * H_ + ((q8 + 64) ^ swzm));            \
        f16x8 hB3 = *(const f16x8*)(HCUR + c * H_ + ((q8 + 96) ^ swzm));            \
        f32x4 aR0 = {(float)GR0[0], (float)GR0[1], (float)GR0[2], (float)GR0[3]};   \
        f32x4 aR1 = {(float)GR1[0], (float)GR1[1], (float)GR1[2], (float)GR1[3]};   \
        f32x4 aZ0 = {(float)GZ0[0], (float)GZ0[1], (float)GZ0[2], (float)GZ0[3]};   \
        f32x4 aZ1 = {(float)GZ1[0], (float)GZ1[1], (float)GZ1[2], (float)GZ1[3]};   \
        f32x4 aN0 = bN0, aN1 = bN1;                                                 \
        aR0 = __builtin_amdgcn_mfma_f32_16x16x32_f16(WA[0][0][0], hB0, aR0, 0, 0, 0); \
        aR1 = __builtin_amdgcn_mfma_f32_16x16x32_f16(WA[0][1][0], hB0, aR1, 0, 0, 0); \
        aZ0 = __builtin_amdgcn_mfma_f32_16x16x32_f16(WA[1][0][0], hB0, aZ0, 0, 0, 0); \
        aZ1 = __builtin_amdgcn_mfma_f32_16x16x32_f16(WA[1][1][0], hB0, aZ1, 0, 0, 0); \
        aN0 = __builtin_amdgcn_mfma_f32_16x16x32_f16(WA[2][0][0], hB0, aN0, 0, 0, 0); \
        aN1 = __builtin_amdgcn_mfma_f32_16x16x32_f16(WA[2][1][0], hB0, aN1, 0, 0, 0); \
        aR0 = __builtin_amdgcn_mfma_f32_16x16x32_f16(WA[0][0][1], hB1, aR0, 0, 0, 0); \
        aR1 = __builtin_amdgcn_mfma_f32_16x16x32_f16(WA[0][1][1], hB1, aR1, 0, 0, 0); \
        aZ0 = __builtin_amdgcn_mfma_f32_16x16x32_f16(WA[1][0][1], hB1, aZ0, 0, 0, 0); \
        aZ1 = __builtin_amdgcn_mfma_f32_16x16x32_f16(WA[1][1][1], hB1, aZ1, 0, 0, 0); \
        aN0 = __builtin_amdgcn_mfma_f32_16x16x32_f16(WA[2][0][1], hB1, aN0, 0, 0, 0); \
        aN1 = __builtin_amdgcn_mfma_f32_16x16x32_f16(WA[2][1][1], hB1, aN1, 0, 0, 0); \
        aR0 = __builtin_amdgcn_mfma_f32_16x16x32_f16(WA[0][0][2], hB2, aR0, 0, 0, 0); \
        aR1 = __builtin_amdgcn_mfma_f32_16x16x32_f16(WA[0][1][2], hB2, aR1, 0, 0, 0); \
        aZ0 = __builtin_amdgcn_mfma_f32_16x16x32_f16(WA[1][0][2], hB2, aZ0, 0, 0, 0); \
        aZ1 = __builtin_amdgcn_mfma_f32_16x16x32_f16(WA[1][1][2], hB2, aZ1, 0, 0, 0); \
        aN0 = __builtin_amdgcn_mfma_f32_16x16x32_f16(WA[2][0][2], hB2, aN0, 0, 0, 0); \
        aN1 = __builtin_amdgcn_mfma_f32_16x16x32_f16(WA[2][1][2], hB2, aN1, 0, 0, 0); \
        aR0 = __builtin_amdgcn_mfma_f32_16x16x32_f16(WA[0][0][3], hB3, aR0, 0, 0, 0); \
        aR1 = __builtin_amdgcn_mfma_f32_16x16x32_f16(WA[0][1][3], hB3, aR1, 0, 0, 0); \
        aZ0 = __builtin_amdgcn_mfma_f32_16x16x32_f16(WA[1][0][3], hB3, aZ0, 0, 0, 0); \
        aZ1 = __builtin_amdgcn_mfma_f32_16x16x32_f16(WA[1][1][3], hB3, aZ1, 0, 0, 0); \
        aN0 = __builtin_amdgcn_mfma_f32_16x16x32_f16(WA[2][0][3], hB3, aN0, 0, 0, 0); \
        aN1 = __builtin_amdgcn_mfma_f32_16x16x32_f16(WA[2][1][3], hB3, aN1, 0, 0, 0); \
        float rg0 = __builtin_amdgcn_rcpf(1.f + __builtin_amdgcn_exp2f(-aR0[0]));   \
        float rg1 = __builtin_amdgcn_rcpf(1.f + __builtin_amdgcn_exp2f(-aR0[1]));   \
        float rg2 = __builtin_amdgcn_rcpf(1.f + __builtin_amdgcn_exp2f(-aR0[2]));   \
        float rg3 = __builtin_amdgcn_rcpf(1.f + __builtin_amdgcn_exp2f(-aR0[3]));   \
        float rg4 = __builtin_amdgcn_rcpf(1.f + __builtin_amdgcn_exp2f(-aR1[0]));   \
        float rg5 = __builtin_amdgcn_rcpf(1.f + __builtin_amdgcn_exp2f(-aR1[1]));   \
        float rg6 = __builtin_amdgcn_rcpf(1.f + __builtin_amdgcn_exp2f(-aR1[2]));   \
        float rg7 = __builtin_amdgcn_rcpf(1.f + __builtin_amdgcn_exp2f(-aR1[3]));   \
        float zg0 = __builtin_amdgcn_rcpf(1.f + __builtin_amdgcn_exp2f(-aZ0[0]));   \
        float zg1 = __builtin_amdgcn_rcpf(1.f + __builtin_amdgcn_exp2f(-aZ0[1]));   \
        float zg2 = __builtin_amdgcn_rcpf(1.f + __builtin_amdgcn_exp2f(-aZ0[2]));   \
        float zg3 = __builtin_amdgcn_rcpf(1.f + __builtin_amdgcn_exp2f(-aZ0[3]));   \
        float zg4 = __builtin_amdgcn_rcpf(1.f + __builtin_amdgcn_exp2f(-aZ1[0]));   \
        float zg5 = __builtin_amdgcn_rcpf(1.f + __builtin_amdgcn_exp2f(-aZ1[1]));   \
        float zg6 = __builtin_amdgcn_rcpf(1.f + __builtin_amdgcn_exp2f(-aZ1[2]));   \
        float zg7 = __builtin_amdgcn_rcpf(1.f + __builtin_amdgcn_exp2f(-aZ1[3]));   \
        float tn0 = fmaf(rg0, aN0[0], (float)GN0[0]);                               \
        float tn1 = fmaf(rg1, aN0[1], (float)GN0[1]);                               \
        float tn2 = fmaf(rg2, aN0[2], (float)GN0[2]);                               \
        float tn3 = fmaf(rg3, aN0[3], (float)GN0[3]);                               \
        float tn4 = fmaf(rg4, aN1[0], (float)GN1[0]);                               \
        float tn5 = fmaf(rg5, aN1[1], (float)GN1[1]);                               \
        float tn6 = fmaf(rg6, aN1[2], (float)GN1[2]);                               \
        float tn7 = fmaf(rg7, aN1[3], (float)GN1[3]);                               \
        float ng0 = fmaf(2.f, __builtin_amdgcn_rcpf(1.f + __builtin_amdgcn_exp2f(-tn0)), -1.f); \
        float ng1 = fmaf(2.f, __builtin_amdgcn_rcpf(1.f + __builtin_amdgcn_exp2f(-tn1)), -1.f); \
        float ng2 = fmaf(2.f, __builtin_amdgcn_rcpf(1.f + __builtin_amdgcn_exp2f(-tn2)), -1.f); \
        float ng3 = fmaf(2.f, __builtin_amdgcn_rcpf(1.f + __builtin_amdgcn_exp2f(-tn3)), -1.f); \
        float ng4 = fmaf(2.f, __builtin_amdgcn_rcpf(1.f + __builtin_amdgcn_exp2f(-tn4)), -1.f); \
        float ng5 = fmaf(2.f, __builtin_amdgcn_rcpf(1.f + __builtin_amdgcn_exp2f(-tn5)), -1.f); \
        float ng6 = fmaf(2.f, __builtin_amdgcn_rcpf(1.f + __builtin_amdgcn_exp2f(-tn6)), -1.f); \
        float ng7 = fmaf(2.f, __builtin_amdgcn_rcpf(1.f + __builtin_amdgcn_exp2f(-tn7)), -1.f); \
        hp00 = fmaf(zg0, hp00 - ng0, ng0);                                          \
        hp01 = fmaf(zg1, hp01 - ng1, ng1);                                          \
        hp02 = fmaf(zg2, hp02 - ng2, ng2);                                          \
        hp03 = fmaf(zg3, hp03 - ng3, ng3);                                          \
        hp10 = fmaf(zg4, hp10 - ng4, ng4);                                          \
        hp11 = fmaf(zg5, hp11 - ng5, ng5);                                          \
        hp12 = fmaf(zg6, hp12 - ng6, ng6);                                          \
        hp13 = fmaf(zg7, hp13 - ng7, ng7);                                          \
        f16x4 hv0 = {(f16)hp00, (f16)hp01, (f16)hp02, (f16)hp03};                   \
        f16x4 hv1 = {(f16)hp10, (f16)hp11, (f16)hp12, (f16)hp13};                   \
        *(f16x4*)(HNEXT + c * H_ + (uD0 ^ swzm)) = hv0;                             \
        *(f16x4*)(HNEXT + c * H_ + (uD1 ^ swzm)) = hv1;                             \
    }

    for (int l = 0; l < L_; l += 2) {
        // ---- even step l: read hb0, write hb1; prefetch gi[l+1] (contiguous/wave) ----
        {
            const f16* gn = gbase + (size_t)(l + 1) * 6144;
            gR0o = *(const f16x4*)(gn + 0);
            gR1o = *(const f16x4*)(gn + 256);
            gZ0o = *(const f16x4*)(gn + 2048);
            gZ1o = *(const f16x4*)(gn + 2304);
            gN0o = *(const f16x4*)(gn + 4096);
            gN1o = *(const f16x4*)(gn + 4352);
        }
        GRU_STEP(hb0, hb1, gR0e, gR1e, gZ0e, gZ1e, gN0e, gN1e, (l > 0))
        __syncthreads();

        // ---- odd step l+1: read hb1, write hb0; prefetch gi[l+2] ----
        {
            int lp = (l + 2 < L_) ? (l + 2) : (L_ - 1);   // clamp: last reload unused
            const f16* gn = gbase + (size_t)lp * 6144;
            gR0e = *(const f16x4*)(gn + 0);
            gR1e = *(const f16x4*)(gn + 256);
            gZ0e = *(const f16x4*)(gn + 2048);
            gZ1e = *(const f16x4*)(gn + 2304);
            gN0e = *(const f16x4*)(gn + 4096);
            gN1e = *(const f16x4*)(gn + 4352);
        }
        GRU_STEP(hb1, hb0, gR0o, gR1o, gZ0o, gZ1o, gN0o, gN1o, true)
        __syncthreads();
    }
#undef GRU_STEP

    // final output: h_out(L-1) sits in hb0 (written by step 511), barrier already passed
    {
        f16x8 sv = *(const f16x8*)(hb0 + srow * H_ + (se8 ^ sswz));
        f32x4 o0 = {(float)sv[0], (float)sv[1], (float)sv[2], (float)sv[3]};
        f32x4 o1 = {(float)sv[4], (float)sv[5], (float)sv[6], (float)sv[7]};
        *(f32x4*)op = o0;
        *(f32x4*)(op + 4) = o1;
    }
}

// ---------------- launch ----------------
extern "C" void kernel_launch(void* const* d_in, const int* in_sizes, int n_in,
                              void* d_out, int out_size, void* d_ws, size_t ws_size,
                              hipStream_t stream) {
    (void)in_sizes; (void)n_in;
    const float* cov = (const float*)d_in[0];
    const float* tr  = (const float*)d_in[1];
    const float* oc  = (const float*)d_in[2];
    const float* Wih = (const float*)d_in[3];
    const float* Whh = (const float*)d_in[4];
    const float* bih = (const float*)d_in[5];
    const float* bhh = (const float*)d_in[6];
    const float* g_t = (const float*)d_in[7];
    const float* bt  = (const float*)d_in[8];
    const float* g_o = (const float*)d_in[9];
    const float* bo  = (const float*)d_in[10];
    const float* g_c = (const float*)d_in[11];
    const float* bc  = (const float*)d_in[12];

    float* outA = (float*)d_out;
    float* outB = (float*)d_out + (size_t)B_ * L_ * Co_;

    // workspace: [WAf 72KB | biasF 1.5KB | pad to 128KB | giF f16 (Bs*512*384)]
    f16*   WAf   = (f16*)d_ws;
    float* biasF = (float*)((char*)d_ws + 73728);
    f16*   giF   = (f16*)((char*)d_ws + 131072);

    // normalized f16 input (transposed) lives at the TOP of d_out
    size_t outBytes = (size_t)out_size * 4;
    size_t ihBytes  = (size_t)B_ * L_ * KP * 2;   // 50.3 MB
    f16* inpT = (f16*)((char*)d_out + (outBytes - ihBytes));

    // pick batch split so giF fits in ws
    int S = 8;
    const int cand[4] = {1, 2, 4, 8};
    for (int i = 0; i < 4; i++) {
        size_t need = 131072 + ((size_t)B_ / cand[i]) * L_ * G3 * 2;
        if (need <= ws_size) { S = cand[i]; break; }
    }
    int Bs = B_ / S;

    k_prep<<<dim3(146), dim3(256), 0, stream>>>(Wih, bih, bhh, WAf, biasF);
    k_norm<<<dim3(B_), dim3(256), 0, stream>>>(cov, tr, oc, g_t, bt, g_o, bo, g_c, bc, inpT);

    for (int s = 0; s < S; s++) {
        const f16* Asub = inpT + (size_t)s * Bs * L_ * KP;
        k_gemm<<<dim3((Bs / 16) * 128), dim3(256), 0, stream>>>(Asub, WAf, biasF, giF);
        k_scan_mfma<<<dim3(Bs / R_), dim3(256), 0, stream>>>(giF, Whh, bhh, outA, outB, s * Bs);
    }
}

// Round 7
// 626.406 us; speedup vs baseline: 1.2274x; 1.2274x over previous
//
#include <hip/hip_runtime.h>

typedef _Float16 f16;
typedef _Float16 f16x8 __attribute__((ext_vector_type(8)));
typedef _Float16 f16x4 __attribute__((ext_vector_type(4)));
typedef float f32x4 __attribute__((ext_vector_type(4)));

#define B_ 512
#define L_ 512
#define Cc_ 64
#define Ct_ 16
#define Co_ 8
#define H_ 128
#define IN_ 88
#define KP 96       // padded K for MFMA
#define G3 384      // 3*H
#define R_ 16       // batch rows per scan block / gemm tile

#define L2E  1.44269504088896f   // log2(e)
#define L2E2 2.88539008177793f   // 2*log2(e)

// Fragment-ordered gi: giF[g0][l][n0=0..23][q=0..3][c=0..15][e=0..3] (f16)
//   unit u = n0*16 + 4q + e, gate g = n0>>3, batch b = g0*16 + c.

// LDS-only barrier: ds_writes drained, but NO vmcnt(0) drain (gi loads / output
// stores keep flying across the barrier). sched_barrier(0) pins ds_reads after.
#define BAR() do { asm volatile("s_waitcnt lgkmcnt(0)" ::: "memory"); \
                   __builtin_amdgcn_s_barrier();                      \
                   __builtin_amdgcn_sched_barrier(0); } while (0)

// ---------------- K0: W_ih -> A-fragment order (scaled); bias -> f32 (scaled, b_hh folded) ----
__global__ void k_prep(const float* __restrict__ Wih,
                       const float* __restrict__ bih, const float* __restrict__ bhh,
                       f16* __restrict__ WAf, float* __restrict__ biasF) {
    int idx = blockIdx.x * 256 + threadIdx.x;
    if (idx < G3 * KP) {                       // 36864 WAf elements
        int n0 = idx / 1536;
        int rem = idx - n0 * 1536;
        int ks = rem >> 9;
        int rem2 = rem & 511;
        int lane = rem2 >> 3, j = rem2 & 7;
        int unit = n0 * 16 + (lane & 15);
        int k = ((lane >> 4) << 3) + 32 * ks + j;
        float s = (n0 < 16) ? L2E : L2E2;
        WAf[idx] = (k < IN_) ? (f16)(Wih[unit * IN_ + k] * s) : (f16)0.f;
    } else if (idx < G3 * KP + G3) {           // 384 biases
        int u = idx - G3 * KP;
        biasF[u] = (u < 256) ? (bih[u] + bhh[u]) * L2E : bih[u] * L2E2;
    }
}

// ---------------- K1: time-norm + concat -> f16, TRANSPOSED [g0][l][c][96] ----------------
__global__ __launch_bounds__(256) void k_norm(
        const float* __restrict__ cov, const float* __restrict__ tr, const float* __restrict__ oc,
        const float* __restrict__ g_t, const float* __restrict__ bt,
        const float* __restrict__ g_o, const float* __restrict__ bo,
        const float* __restrict__ g_c, const float* __restrict__ bc,
        f16* __restrict__ inpT) {
    int b = blockIdx.x, t = threadIdx.x;
    __shared__ float ps[256], ps2[256];
    __shared__ float sc[88], sh[88];   // concat order: t[0:16), o[16:24), c[24:88)

    { // covariates, C=64, 4 l-groups
        int c = t & 63, lg = t >> 6;
        const float* p = cov + (size_t)b * L_ * Cc_ + c;
        float s = 0.f, s2 = 0.f;
        for (int i = lg; i < L_; i += 4) { float v = p[(size_t)i * Cc_]; s += v; s2 += v * v; }
        ps[t] = s; ps2[t] = s2; __syncthreads();
        if (t < 64) {
            float S = 0.f, S2 = 0.f;
            for (int g = 0; g < 4; g++) { S += ps[t + 64 * g]; S2 += ps2[t + 64 * g]; }
            float m = S * (1.f / L_), v = S2 * (1.f / L_) - m * m;
            float inv = rsqrtf(v + 1e-5f);
            float gg = g_c[t] * inv;
            sc[24 + t] = gg; sh[24 + t] = bc[t] - m * gg;
        }
        __syncthreads();
    }
    { // treatments, C=16, 16 l-groups
        int c = t & 15, lg = t >> 4;
        const float* p = tr + (size_t)b * L_ * Ct_ + c;
        float s = 0.f, s2 = 0.f;
        for (int i = lg; i < L_; i += 16) { float v = p[(size_t)i * Ct_]; s += v; s2 += v * v; }
        ps[t] = s; ps2[t] = s2; __syncthreads();
        if (t < 16) {
            float S = 0.f, S2 = 0.f;
            for (int g = 0; g < 16; g++) { S += ps[t + 16 * g]; S2 += ps2[t + 16 * g]; }
            float m = S * (1.f / L_), v = S2 * (1.f / L_) - m * m;
            float inv = rsqrtf(v + 1e-5f);
            float gg = g_t[t] * inv;
            sc[t] = gg; sh[t] = bt[t] - m * gg;
        }
        __syncthreads();
    }
    { // outcomes, C=8, 32 l-groups
        int c = t & 7, lg = t >> 3;
        const float* p = oc + (size_t)b * L_ * Co_ + c;
        float s = 0.f, s2 = 0.f;
        for (int i = lg; i < L_; i += 32) { float v = p[(size_t)i * Co_]; s += v; s2 += v * v; }
        ps[t] = s; ps2[t] = s2; __syncthreads();
        if (t < 8) {
            float S = 0.f, S2 = 0.f;
            for (int g = 0; g < 32; g++) { S += ps[t + 8 * g]; S2 += ps2[t + 8 * g]; }
            float m = S * (1.f / L_), v = S2 * (1.f / L_) - m * m;
            float inv = rsqrtf(v + 1e-5f);
            float gg = g_o[t] * inv;
            sc[16 + t] = gg; sh[16 + t] = bo[t] - m * gg;
        }
        __syncthreads();
    }
    // phase B: normalize + concat + pad -> inpT[((b>>4)*512 + l)*16 + (b&15)][96]
    f16* outp = inpT + ((size_t)(b >> 4) * L_ * 16 + (b & 15)) * KP;
    for (int idx = t; idx < L_ * KP; idx += 256) {
        int l = idx / KP, cc = idx % KP;
        float y = 0.f;
        if (cc < 88) {
            float x;
            if (cc < 16)      x = tr[((size_t)b * L_ + l) * Ct_ + cc];
            else if (cc < 24) x = oc[((size_t)b * L_ + l) * Co_ + (cc - 16)];
            else              x = cov[((size_t)b * L_ + l) * Cc_ + (cc - 24)];
            y = x * sc[cc] + sh[cc];
        }
        outp[(size_t)l * 16 * KP + cc] = (f16)y;
    }
}

// ---------------- K2: gi GEMM, fragment-ordered output. ---------------------------------
__global__ __launch_bounds__(256) void k_gemm(
        const f16* __restrict__ inpT, const f16* __restrict__ WAf,
        const float* __restrict__ biasF, f16* __restrict__ giF) {
    const int g0 = blockIdx.x >> 7;
    const int l  = ((blockIdx.x & 127) << 2) + (threadIdx.x >> 6);
    const int lane = threadIdx.x & 63;
    const int c = lane & 15, q = lane >> 4;

    const f16* bp = inpT + (((size_t)g0 * L_ + l) * 16 + c) * KP + q * 8;
    f16x8 x0 = *(const f16x8*)(bp);
    f16x8 x1 = *(const f16x8*)(bp + 32);
    f16x8 x2 = *(const f16x8*)(bp + 64);

    const f16x8* wa = (const f16x8*)WAf;
    f16* gout = giF + ((size_t)g0 * L_ + l) * 24 * 256 + q * 64 + c * 4;

    #pragma unroll 4
    for (int n0 = 0; n0 < 24; n0++) {
        f16x8 a0 = wa[(n0 * 3 + 0) * 64 + lane];
        f16x8 a1 = wa[(n0 * 3 + 1) * 64 + lane];
        f16x8 a2 = wa[(n0 * 3 + 2) * 64 + lane];
        f32x4 acc = *(const f32x4*)(biasF + n0 * 16 + q * 4);
        acc = __builtin_amdgcn_mfma_f32_16x16x32_f16(a0, x0, acc, 0, 0, 0);
        acc = __builtin_amdgcn_mfma_f32_16x16x32_f16(a1, x1, acc, 0, 0, 0);
        acc = __builtin_amdgcn_mfma_f32_16x16x32_f16(a2, x2, acc, 0, 0, 0);
        f16x4 st = {(f16)acc[0], (f16)acc[1], (f16)acc[2], (f16)acc[3]};
        *(f16x4*)(gout + n0 * 256) = st;
    }
}

// ---------------- K3: GRU scan via MFMA. 16 rows/block, 8 waves (2/SIMD). ----------------
// Round-7 deltas vs the proven 361us round-5 kernel (ONLY these two):
//  (1) full-width XOR swizzle mask (c&15)<<3: row base of hb is bank-0-aligned
//      (256B stride), so (c&7) left 8 lanes per 16B slot; (c&15) spreads to 4.
//  (2) BAR(): lgkmcnt-only barrier — no vmcnt(0) drain of gi loads/output stores.
__global__ __launch_bounds__(512, 2) void k_scan_mfma(
        const f16* __restrict__ giF, const float* __restrict__ Whh, const float* __restrict__ bhh,
        float* __restrict__ outA, float* __restrict__ outB, int rowBase) {
    const int t = threadIdx.x;
    const int w = t >> 6;          // wave 0..7: owns hidden units [16w, 16w+16)
    const int lane = t & 63;
    const int c = lane & 15;       // batch row within tile
    const int q = lane >> 4;       // 0..3
    const int q8 = q * 8;
    const int uD = 16 * w + q * 4;              // this lane's unit base in D

    __shared__ f16 hb0[R_ * H_];                // 4KB each, swizzled [b][k^((b&15)<<3)]
    __shared__ f16 hb1[R_ * H_];

    // persistent W_hh A-fragments: unit = 16w + c, k = q8 + 32ks + j  (f32 -> f16, scaled)
    f16x8 WA[3][4];
    #pragma unroll
    for (int g = 0; g < 3; g++) {
        float s = (g < 2) ? L2E : L2E2;
        #pragma unroll
        for (int ks = 0; ks < 4; ks++) {
            const float* wp = Whh + (size_t)(g * H_ + 16 * w + c) * H_ + q8 + 32 * ks;
            f16x8 v;
            #pragma unroll
            for (int j = 0; j < 8; j++) v[j] = (f16)(wp[j] * s);
            WA[g][ks] = v;
        }
    }
    // n-gate b_hh, pre-scaled — becomes the aN accumulator init
    const f32x4 bN = { L2E2 * bhh[2 * H_ + uD + 0], L2E2 * bhh[2 * H_ + uD + 1],
                       L2E2 * bhh[2 * H_ + uD + 2], L2E2 * bhh[2 * H_ + uD + 3] };

    for (int i = t; i < R_ * H_; i += 512) hb0[i] = (f16)0.f;
    float hp0 = 0.f, hp1 = 0.f, hp2 = 0.f, hp3 = 0.f;

    // ---- coalesced output staging: thread -> (row, 4 contiguous units) ----
    const int orow = t >> 5;               // 0..15 (block-local row)
    const int oe4  = (t & 31) * 4;         // unit base 0..124
    const int oswz = (orow & 15) << 3;
    const int grow = rowBase + blockIdx.x * R_ + orow;
    float* op; size_t ost;
    if (oe4 < Co_) { op = outA + (size_t)grow * L_ * Co_ + oe4;            ost = Co_; }
    else           { op = outB + (size_t)grow * L_ * (H_ - Co_) + (oe4 - Co_); ost = H_ - Co_; }

    const int swzm = (c & 15) << 3;             // full-width XOR swizzle (f16 idx bits 3..6)
    // fragment-ordered gi pointer: wave-contiguous 512B loads
    const f16* gbase = giF + (size_t)blockIdx.x * L_ * 24 * 256 + w * 256 + q * 64 + c * 4;

    // preload gi[0] into E buffers
    f16x4 gRe = *(const f16x4*)(gbase + 0 * 2048);
    f16x4 gZe = *(const f16x4*)(gbase + 1 * 2048);
    f16x4 gNe = *(const f16x4*)(gbase + 2 * 2048);
    f16x4 gRo, gZo, gNo;

    BAR();

#define GRU_STEP(HCUR, HNEXT, GR, GZ, GN, DOSTAGE)                                  \
    {                                                                               \
        if (DOSTAGE) {  /* store h_out(prev step), coalesced, f16-rounded */        \
            f16x4 hv = *(const f16x4*)(HCUR + orow * H_ + (oe4 ^ oswz));            \
            f32x4 ov = {(float)hv[0], (float)hv[1], (float)hv[2], (float)hv[3]};    \
            *(f32x4*)op = ov;                                                       \
            op += ost;                                                              \
        }                                                                           \
        f16x8 hB0 = *(const f16x8*)(HCUR + c * H_ + ((q8 +  0) ^ swzm));            \
        f16x8 hB1 = *(const f16x8*)(HCUR + c * H_ + ((q8 + 32) ^ swzm));            \
        f16x8 hB2 = *(const f16x8*)(HCUR + c * H_ + ((q8 + 64) ^ swzm));            \
        f16x8 hB3 = *(const f16x8*)(HCUR + c * H_ + ((q8 + 96) ^ swzm));            \
        f32x4 aR = {(float)GR[0], (float)GR[1], (float)GR[2], (float)GR[3]};        \
        f32x4 aZ = {(float)GZ[0], (float)GZ[1], (float)GZ[2], (float)GZ[3]};        \
        f32x4 aN = bN;                                                              \
        aR = __builtin_amdgcn_mfma_f32_16x16x32_f16(WA[0][0], hB0, aR, 0, 0, 0);    \
        aZ = __builtin_amdgcn_mfma_f32_16x16x32_f16(WA[1][0], hB0, aZ, 0, 0, 0);    \
        aN = __builtin_amdgcn_mfma_f32_16x16x32_f16(WA[2][0], hB0, aN, 0, 0, 0);    \
        aR = __builtin_amdgcn_mfma_f32_16x16x32_f16(WA[0][1], hB1, aR, 0, 0, 0);    \
        aZ = __builtin_amdgcn_mfma_f32_16x16x32_f16(WA[1][1], hB1, aZ, 0, 0, 0);    \
        aN = __builtin_amdgcn_mfma_f32_16x16x32_f16(WA[2][1], hB1, aN, 0, 0, 0);    \
        aR = __builtin_amdgcn_mfma_f32_16x16x32_f16(WA[0][2], hB2, aR, 0, 0, 0);    \
        aZ = __builtin_amdgcn_mfma_f32_16x16x32_f16(WA[1][2], hB2, aZ, 0, 0, 0);    \
        aN = __builtin_amdgcn_mfma_f32_16x16x32_f16(WA[2][2], hB2, aN, 0, 0, 0);    \
        aR = __builtin_amdgcn_mfma_f32_16x16x32_f16(WA[0][3], hB3, aR, 0, 0, 0);    \
        aZ = __builtin_amdgcn_mfma_f32_16x16x32_f16(WA[1][3], hB3, aZ, 0, 0, 0);    \
        aN = __builtin_amdgcn_mfma_f32_16x16x32_f16(WA[2][3], hB3, aN, 0, 0, 0);    \
        float rg0 = __builtin_amdgcn_rcpf(1.f + __builtin_amdgcn_exp2f(-aR[0]));    \
        float rg1 = __builtin_amdgcn_rcpf(1.f + __builtin_amdgcn_exp2f(-aR[1]));    \
        float rg2 = __builtin_amdgcn_rcpf(1.f + __builtin_amdgcn_exp2f(-aR[2]));    \
        float rg3 = __builtin_amdgcn_rcpf(1.f + __builtin_amdgcn_exp2f(-aR[3]));    \
        float zg0 = __builtin_amdgcn_rcpf(1.f + __builtin_amdgcn_exp2f(-aZ[0]));    \
        float zg1 = __builtin_amdgcn_rcpf(1.f + __builtin_amdgcn_exp2f(-aZ[1]));    \
        float zg2 = __builtin_amdgcn_rcpf(1.f + __builtin_amdgcn_exp2f(-aZ[2]));    \
        float zg3 = __builtin_amdgcn_rcpf(1.f + __builtin_amdgcn_exp2f(-aZ[3]));    \
        float tn0 = fmaf(rg0, aN[0], (float)GN[0]);                                 \
        float tn1 = fmaf(rg1, aN[1], (float)GN[1]);                                 \
        float tn2 = fmaf(rg2, aN[2], (float)GN[2]);                                 \
        float tn3 = fmaf(rg3, aN[3], (float)GN[3]);                                 \
        float ng0 = fmaf(2.f, __builtin_amdgcn_rcpf(1.f + __builtin_amdgcn_exp2f(-tn0)), -1.f); \
        float ng1 = fmaf(2.f, __builtin_amdgcn_rcpf(1.f + __builtin_amdgcn_exp2f(-tn1)), -1.f); \
        float ng2 = fmaf(2.f, __builtin_amdgcn_rcpf(1.f + __builtin_amdgcn_exp2f(-tn2)), -1.f); \
        float ng3 = fmaf(2.f, __builtin_amdgcn_rcpf(1.f + __builtin_amdgcn_exp2f(-tn3)), -1.f); \
        hp0 = fmaf(zg0, hp0 - ng0, ng0);                                            \
        hp1 = fmaf(zg1, hp1 - ng1, ng1);                                            \
        hp2 = fmaf(zg2, hp2 - ng2, ng2);                                            \
        hp3 = fmaf(zg3, hp3 - ng3, ng3);                                            \
        f16x4 hv16 = {(f16)hp0, (f16)hp1, (f16)hp2, (f16)hp3};                      \
        *(f16x4*)(HNEXT + c * H_ + (uD ^ swzm)) = hv16;                             \
    }

    for (int l = 0; l < L_; l += 2) {
        // ---- even step l: read hb0, write hb1; prefetch gi[l+1] (contiguous/wave) ----
        {
            const f16* gn = gbase + (size_t)(l + 1) * 6144;
            gRo = *(const f16x4*)(gn + 0 * 2048);
            gZo = *(const f16x4*)(gn + 1 * 2048);
            gNo = *(const f16x4*)(gn + 2 * 2048);
        }
        GRU_STEP(hb0, hb1, gRe, gZe, gNe, (l > 0))
        BAR();

        // ---- odd step l+1: read hb1, write hb0; prefetch gi[l+2] ----
        {
            int lp = (l + 2 < L_) ? (l + 2) : (L_ - 1);   // clamp: last reload unused
            const f16* gn = gbase + (size_t)lp * 6144;
            gRe = *(const f16x4*)(gn + 0 * 2048);
            gZe = *(const f16x4*)(gn + 1 * 2048);
            gNe = *(const f16x4*)(gn + 2 * 2048);
        }
        GRU_STEP(hb1, hb0, gRo, gZo, gNo, true)
        BAR();
    }
#undef GRU_STEP

    // final output: h_out(L-1) sits in hb0 (written by step 511), barrier already passed
    {
        f16x4 hv = *(const f16x4*)(hb0 + orow * H_ + (oe4 ^ oswz));
        f32x4 ov = {(float)hv[0], (float)hv[1], (float)hv[2], (float)hv[3]};
        *(f32x4*)op = ov;
    }
}

// ---------------- launch ----------------
extern "C" void kernel_launch(void* const* d_in, const int* in_sizes, int n_in,
                              void* d_out, int out_size, void* d_ws, size_t ws_size,
                              hipStream_t stream) {
    (void)in_sizes; (void)n_in;
    const float* cov = (const float*)d_in[0];
    const float* tr  = (const float*)d_in[1];
    const float* oc  = (const float*)d_in[2];
    const float* Wih = (const float*)d_in[3];
    const float* Whh = (const float*)d_in[4];
    const float* bih = (const float*)d_in[5];
    const float* bhh = (const float*)d_in[6];
    const float* g_t = (const float*)d_in[7];
    const float* bt  = (const float*)d_in[8];
    const float* g_o = (const float*)d_in[9];
    const float* bo  = (const float*)d_in[10];
    const float* g_c = (const float*)d_in[11];
    const float* bc  = (const float*)d_in[12];

    float* outA = (float*)d_out;
    float* outB = (float*)d_out + (size_t)B_ * L_ * Co_;

    // workspace: [WAf 72KB | biasF 1.5KB | pad to 128KB | giF f16 (Bs*512*384)]
    f16*   WAf   = (f16*)d_ws;
    float* biasF = (float*)((char*)d_ws + 73728);
    f16*   giF   = (f16*)((char*)d_ws + 131072);

    // normalized f16 input (transposed) lives at the TOP of d_out
    size_t outBytes = (size_t)out_size * 4;
    size_t ihBytes  = (size_t)B_ * L_ * KP * 2;   // 50.3 MB
    f16* inpT = (f16*)((char*)d_out + (outBytes - ihBytes));

    // pick batch split so giF fits in ws
    int S = 8;
    const int cand[4] = {1, 2, 4, 8};
    for (int i = 0; i < 4; i++) {
        size_t need = 131072 + ((size_t)B_ / cand[i]) * L_ * G3 * 2;
        if (need <= ws_size) { S = cand[i]; break; }
    }
    int Bs = B_ / S;

    k_prep<<<dim3(146), dim3(256), 0, stream>>>(Wih, bih, bhh, WAf, biasF);
    k_norm<<<dim3(B_), dim3(256), 0, stream>>>(cov, tr, oc, g_t, bt, g_o, bo, g_c, bc, inpT);

    for (int s = 0; s < S; s++) {
        const f16* Asub = inpT + (size_t)s * Bs * L_ * KP;
        k_gemm<<<dim3((Bs / 16) * 128), dim3(256), 0, stream>>>(Asub, WAf, biasF, giF);
        k_scan_mfma<<<dim3(Bs / R_), dim3(512), 0, stream>>>(giF, Whh, bhh, outA, outB, s * Bs);
    }
}